// Round 19
// baseline (79.953 us; speedup 1.0000x reference)
//
#include <hip/hip_runtime.h>
#include <math.h>

#define L 250000
#define FEAT 100
#define HID 50
#define HS 165
#define CQ 50257
#define EXTV 1000
#define NOUT (CQ + EXTV)   // 51257

#define NBLK23 2048
#define NW23 (NBLK23 * 4)   // 8192 waves, ~30-31 rows/wave
#define NBLK5R ((NOUT + 63) / 64)   // 801 blocks, 64 rows/block, 4 thr/row
#define NCOL 101            // 100 ct cols + denom

// workspace float offsets
#define WS_Q     0      // 100
#define WS_P1    100
#define WS_P2    101
#define WS_SCALE 102    // p2/denom
#define WS_DENOM 103
#define WS_CT    104    // 100
#define WS_ET    204    // 200 (16B aligned)
#define WS_H     404    // 50
#define WS_ADD   512    // 51257 raw scatter accumulator
#define WS_OUT   51776  // 51257 pre-logsoftmax vocab
#define WS_MS    103040 // NBLK5R*2 (m,s) pairs (1602 floats)
#define WS_PT    104960 // 101*2048 block partials [col][blk]

__device__ __forceinline__ float sigm(float x) { return 1.f / (1.f + expf(-x)); }

// ---------------- K1: LSTM step + q + p1/p2 ; zero add_buf ----------------
__global__ void k1_lstm(const float* __restrict__ y, const float* __restrict__ h0,
                        const float* __restrict__ c0,
                        const float* __restrict__ W_ih, const float* __restrict__ W_hh,
                        const float* __restrict__ b_ih, const float* __restrict__ b_hh,
                        const float* __restrict__ w_h_W, const float* __restrict__ w_h_b,
                        const float* __restrict__ l3_W, const float* __restrict__ l3_b,
                        const float* __restrict__ l4_W, const float* __restrict__ l4_b,
                        float* __restrict__ ws, float* __restrict__ out) {
    int t = threadIdx.x;
    if (blockIdx.x != 0) {
        float* add = ws + WS_ADD;
        for (int i = (blockIdx.x - 1) * 256 + t; i < NOUT; i += 63 * 256) add[i] = 0.f;
        return;
    }
    __shared__ float s_y[HS], s_h[HID], s_c[HID], s_g[4 * HID], s_hn[HID];
    if (t < HS) s_y[t] = y[t];
    if (t < HID) { s_h[t] = h0[t]; s_c[t] = c0[t]; }
    __syncthreads();
    if (t < 4 * HID) {
        float acc = b_ih[t] + b_hh[t];
        const float* wi = W_ih + t * HS;
        for (int k = 0; k < HS; ++k) acc += wi[k] * s_y[k];
        const float* wh = W_hh + t * HID;
        for (int k = 0; k < HID; ++k) acc += wh[k] * s_h[k];
        s_g[t] = acc;
    }
    __syncthreads();
    if (t < HID) {
        float ig = sigm(s_g[t]);
        float fg = sigm(s_g[HID + t]);
        float gg = tanhf(s_g[2 * HID + t]);
        float og = sigm(s_g[3 * HID + t]);
        float cn = fg * s_c[t] + ig * gg;
        float hn = og * tanhf(cn);
        s_hn[t] = hn;
        ws[WS_H + t] = hn;
        out[NOUT + t] = hn;          // h_new output
        out[NOUT + HID + t] = cn;    // c_new output
    }
    __syncthreads();
    if (t < FEAT) {
        float acc = w_h_b[t];
        const float* w = w_h_W + t * HID;
        for (int k = 0; k < HID; ++k) acc += w[k] * s_hn[k];
        ws[WS_Q + t] = acc;
    }
    if (t == 200) {
        float acc = l3_b[0];
        for (int k = 0; k < HID; ++k) acc += l3_W[k] * s_hn[k];
        ws[WS_P1] = sigm(acc);
    }
    if (t == 201) {
        float acc = l4_b[0];
        for (int k = 0; k < HID; ++k) acc += l4_W[k] * s_hn[k];
        ws[WS_P2] = sigm(acc);
    }
}

// ------- K23: half-wave-per-row, float4 column ownership + prefetch. --------
// Lane l32<25 owns cols [4*l32, 4*l32+4); lanes 0-31 = row A, 32-63 = row B.
// One float4 load per row per thread; next-8-rows prefetch double-buffer.
// 5-level butterfly per pair; wave-wide scatter at end.
__global__ void __launch_bounds__(256, 8)
k23_fused(const float* __restrict__ H, const int* __restrict__ cont,
          float* __restrict__ ws, float* __restrict__ pt) {
    __shared__ float s_ct[4][FEAT];
    __shared__ float s_d[4];
    int t = threadIdx.x;
    int w = t >> 6, lane = t & 63;
    int l32 = lane & 31, half = lane >> 5;
    long wid = (long)blockIdx.x * 4 + w;
    long r0 = (wid * L) / NW23;
    long r1 = ((wid + 1) * L) / NW23;

    float4 q4 = make_float4(0.f, 0.f, 0.f, 0.f);
    if (l32 < 25) q4 = ((const float4*)(ws + WS_Q))[l32];

    float4 cacc = make_float4(0.f, 0.f, 0.f, 0.f);
    float dacc = 0.f, my_e = 0.f;

    float4 hv[4];
#pragma unroll
    for (int p = 0; p < 4; ++p) {
        long row = r0 + 2 * p + half;
        hv[p] = make_float4(0.f, 0.f, 0.f, 0.f);
        if (row < r1 && l32 < 25)
            hv[p] = ((const float4*)(H + row * FEAT))[l32];
    }
    for (long r = r0; r < r1; r += 8) {
        // ---- prefetch next 8 rows while computing current ----
        float4 hn[4];
#pragma unroll
        for (int p = 0; p < 4; ++p) {
            long row = r + 8 + 2 * p + half;
            hn[p] = make_float4(0.f, 0.f, 0.f, 0.f);
            if (row < r1 && l32 < 25)
                hn[p] = ((const float4*)(H + row * FEAT))[l32];
        }
        float pd[4];
#pragma unroll
        for (int p = 0; p < 4; ++p)
            pd[p] = hv[p].x * q4.x + hv[p].y * q4.y + hv[p].z * q4.z + hv[p].w * q4.w;
#pragma unroll
        for (int o = 1; o < 32; o <<= 1) {
#pragma unroll
            for (int p = 0; p < 4; ++p) pd[p] += __shfl_xor(pd[p], o);
        }
#pragma unroll
        for (int p = 0; p < 4; ++p) {
            float e = expf(pd[p]);            // own-half row's e
            float eo = __shfl_xor(e, 32);     // other half's e
            float eA = half ? eo : e;
            float eB = half ? e : eo;
            long rA = r + 2 * p, rB = rA + 1;
            if (rA < r1) {
                dacc += eA;
                my_e = ((int)(rA - r0) == lane) ? eA : my_e;
            }
            if (rB < r1) {
                dacc += eB;
                my_e = ((int)(rB - r0) == lane) ? eB : my_e;
            }
            cacc.x += e * hv[p].x;
            cacc.y += e * hv[p].y;
            cacc.z += e * hv[p].z;
            cacc.w += e * hv[p].w;
        }
#pragma unroll
        for (int p = 0; p < 4; ++p) hv[p] = hn[p];
    }
    // combine halves (rows A and B share col ownership)
    cacc.x += __shfl_xor(cacc.x, 32);
    cacc.y += __shfl_xor(cacc.y, 32);
    cacc.z += __shfl_xor(cacc.z, 32);
    cacc.w += __shfl_xor(cacc.w, 32);
    // ---- wave-wide scatter: one atomic instruction per wave ----
    int cnt = (int)(r1 - r0);                  // ~30-31 <= 64
    if (lane < cnt) {
        int c = cont[r0 + lane];               // coalesced
        atomicAdd(ws + WS_ADD + c, my_e);
    }
    // ---- block partials ----
    if (half == 0 && l32 < 25) {
        s_ct[w][4 * l32 + 0] = cacc.x;
        s_ct[w][4 * l32 + 1] = cacc.y;
        s_ct[w][4 * l32 + 2] = cacc.z;
        s_ct[w][4 * l32 + 3] = cacc.w;
    }
    if (lane == 0) s_d[w] = dacc;
    __syncthreads();
    if (t < FEAT)
        pt[(size_t)t * NBLK23 + blockIdx.x] =
            s_ct[0][t] + s_ct[1][t] + s_ct[2][t] + s_ct[3][t];
    if (t == FEAT)
        pt[(size_t)FEAT * NBLK23 + blockIdx.x] = s_d[0] + s_d[1] + s_d[2] + s_d[3];
}

// ------- K3r: per-column partial reduce (plain, no fences) ----------
__global__ void k3r_reduce(const float* __restrict__ pt, float* __restrict__ ws) {
    __shared__ float sw[4];
    int col = blockIdx.x;           // 0..100 (100 = denom)
    int t = threadIdx.x;
    const float* p = pt + (size_t)col * NBLK23;
    float s = 0.f;
#pragma unroll
    for (int k = 0; k < NBLK23 / 256; ++k) s += p[t + k * 256];
#pragma unroll
    for (int o = 1; o < 64; o <<= 1) s += __shfl_xor(s, o);
    if ((t & 63) == 0) sw[t >> 6] = s;
    __syncthreads();
    if (t == 0) {
        float tot = sw[0] + sw[1] + sw[2] + sw[3];
        if (col < FEAT) ws[WS_CT + col] = tot;
        else ws[WS_DENOM] = tot;
    }
}

// ------- K4: 1 block: temp = [h ; ct/denom], e_t = sigmoid(l1), scale -------
__global__ void k4_et(const float* __restrict__ l1_W, const float* __restrict__ l1_b,
                      float* __restrict__ ws) {
    __shared__ float s_t[152];
    int t = threadIdx.x;
    float denom = ws[WS_DENOM];
    if (t < HID) s_t[t] = ws[WS_H + t];
    if (t < FEAT) s_t[HID + t] = ws[WS_CT + t] / denom;
    if (t == 0) ws[WS_SCALE] = ws[WS_P2] / denom;
    __syncthreads();
    if (t < 200) {
        float acc = l1_b[t];
        const float* wv = l1_W + t * 150;
        for (int k = 0; k < 150; ++k) acc += wv[k] * s_t[k];
        ws[WS_ET + t] = sigm(acc);
    }
}

// ------- K5: 4-threads-per-row GEMV (64 rows/block), explicit load array for
// MLP; out[r] = p1*(l2_W[r].e_t+b) + scale*add[r]; per-block (m,s) plain-store.
// NO fences, NO atomics, NO last-block work. ---------------------------------
__global__ void __launch_bounds__(256)
k5_vocab(const float* __restrict__ l2_W, const float* __restrict__ l2_b,
         float* __restrict__ ws, float* __restrict__ outv) {
    __shared__ float4 s_e[50];
    __shared__ float s_ms[8];
    int t = threadIdx.x, w = t >> 6, lane = t & 63;
    if (t < 50) s_e[t] = ((const float4*)(ws + WS_ET))[t];
    __syncthreads();
    float p1 = ws[WS_P1], scale = ws[WS_SCALE];
    const float* add = ws + WS_ADD;
    int row = blockIdx.x * 64 + (t >> 2);
    int q = t & 3;
    float m = -1e30f, s = 0.f;
    float acc = 0.f;
    if (row < CQ) {
        const float4* wrow = (const float4*)l2_W + (size_t)row * 50;
        float4 a[13];
#pragma unroll
        for (int j = 0; j < 12; ++j) a[j] = wrow[q + 4 * j];          // 12 independent loads
        a[12] = (q < 2) ? wrow[48 + q] : make_float4(0.f, 0.f, 0.f, 0.f);
#pragma unroll
        for (int j = 0; j < 12; ++j) {
            float4 b = s_e[q + 4 * j];
            acc += a[j].x * b.x + a[j].y * b.y + a[j].z * b.z + a[j].w * b.w;
        }
        if (q < 2) {
            float4 b = s_e[48 + q];
            acc += a[12].x * b.x + a[12].y * b.y + a[12].z * b.z + a[12].w * b.w;
        }
    }
    acc += __shfl_xor(acc, 1);
    acc += __shfl_xor(acc, 2);
    if (q == 0 && row < NOUT) {
        float val = (row < CQ) ? p1 * (acc + l2_b[row]) + scale * add[row]
                               : scale * add[row];
        outv[row] = val;
        m = val; s = 1.f;
    }
    // wave (m,s) butterfly
#pragma unroll
    for (int o = 1; o < 64; o <<= 1) {
        float mb = __shfl_xor(m, o), sb = __shfl_xor(s, o);
        float mn = fmaxf(m, mb);
        s = s * expf(m - mn) + sb * expf(mb - mn);
        m = mn;
    }
    if (lane == 0) { s_ms[w * 2] = m; s_ms[w * 2 + 1] = s; }
    __syncthreads();
    if (t == 0) {
        float mg = s_ms[0], sg = s_ms[1];
        for (int k = 1; k < 4; ++k) {
            float mb = s_ms[2 * k], sb = s_ms[2 * k + 1];
            float mn = fmaxf(mg, mb);
            sg = sg * expf(mg - mn) + sb * expf(mb - mn);
            mg = mn;
        }
        ws[WS_MS + 2 * blockIdx.x] = mg;
        ws[WS_MS + 2 * blockIdx.x + 1] = sg;
    }
}

// ------- K7c: redundant per-block lse reduce (1.6 KB, L2-hit) + subtract -----
__global__ void __launch_bounds__(256)
k7c_final(const float* __restrict__ outv, const float* __restrict__ ws,
          float* __restrict__ dout) {
    __shared__ float s_ms[8];
    __shared__ float s_lse;
    int t = threadIdx.x, w = t >> 6, lane = t & 63;
    const float* msbuf = ws + WS_MS;
    float mg = -1e30f, sg = 0.f;
    for (int k = t; k < NBLK5R; k += 256) {
        float mb = msbuf[2 * k], sb = msbuf[2 * k + 1];
        float mn = fmaxf(mg, mb);
        sg = sg * expf(mg - mn) + sb * expf(mb - mn);
        mg = mn;
    }
#pragma unroll
    for (int o = 1; o < 64; o <<= 1) {
        float mb = __shfl_xor(mg, o), sb = __shfl_xor(sg, o);
        float mn = fmaxf(mg, mb);
        sg = sg * expf(mg - mn) + sb * expf(mb - mn);
        mg = mn;
    }
    if (lane == 0) { s_ms[w * 2] = mg; s_ms[w * 2 + 1] = sg; }
    __syncthreads();
    if (t == 0) {
        float M = s_ms[0], S = s_ms[1];
        for (int k = 1; k < 4; ++k) {
            float mb = s_ms[2 * k], sb = s_ms[2 * k + 1];
            float mn = fmaxf(M, mb);
            S = S * expf(M - mn) + sb * expf(mb - mn);
            M = mn;
        }
        s_lse = M + logf(S);
    }
    __syncthreads();
    int j = blockIdx.x * 256 + t;
    if (j < NOUT) dout[j] = outv[j] - s_lse;
}

extern "C" void kernel_launch(void* const* d_in, const int* in_sizes, int n_in,
                              void* d_out, int out_size, void* d_ws, size_t ws_size,
                              hipStream_t stream) {
    const float* H    = (const float*)d_in[0];
    const float* y    = (const float*)d_in[1];
    const float* h0   = (const float*)d_in[2];
    const float* c0   = (const float*)d_in[3];
    const int*   cont = (const int*)d_in[4];
    // d_in[5] = ext scalar (1000), hardcoded
    const float* W_ih = (const float*)d_in[6];
    const float* W_hh = (const float*)d_in[7];
    const float* b_ih = (const float*)d_in[8];
    const float* b_hh = (const float*)d_in[9];
    const float* w_h_W = (const float*)d_in[10];
    const float* w_h_b = (const float*)d_in[11];
    const float* l1_W = (const float*)d_in[12];
    const float* l1_b = (const float*)d_in[13];
    const float* l2_W = (const float*)d_in[14];
    const float* l2_b = (const float*)d_in[15];
    const float* l3_W = (const float*)d_in[16];
    const float* l3_b = (const float*)d_in[17];
    const float* l4_W = (const float*)d_in[18];
    const float* l4_b = (const float*)d_in[19];

    float* ws  = (float*)d_ws;
    float* out = (float*)d_out;

    k1_lstm<<<64, 256, 0, stream>>>(y, h0, c0, W_ih, W_hh, b_ih, b_hh,
                                    w_h_W, w_h_b, l3_W, l3_b, l4_W, l4_b, ws, out);

    k23_fused<<<NBLK23, 256, 0, stream>>>(H, cont, ws, ws + WS_PT);

    k3r_reduce<<<NCOL, 256, 0, stream>>>(ws + WS_PT, ws);

    k4_et<<<1, 256, 0, stream>>>(l1_W, l1_b, ws);

    k5_vocab<<<NBLK5R, 256, 0, stream>>>(l2_W, l2_b, ws, ws + WS_OUT);

    k7c_final<<<(NOUT + 255) / 256, 256, 0, stream>>>(ws + WS_OUT, ws, out);
}

// Round 20
// 65.801 us; speedup vs baseline: 1.2151x; 1.2151x over previous
//
#include <hip/hip_runtime.h>
#include <math.h>

#define L 250000
#define FEAT 100
#define HID 50
#define HS 165
#define CQ 50257
#define EXTV 1000
#define NOUT (CQ + EXTV)   // 51257

#define NBLK23 2048
#define NW23 (NBLK23 * 4)   // 8192 waves, ~30-31 rows/wave
#define NBLK5R ((NOUT + 63) / 64)   // 801 blocks, 64 rows/block, 4 thr/row
#define NCOL 101            // 100 ct cols + denom

// workspace float offsets
#define WS_Q     0      // 100
#define WS_P1    100
#define WS_P2    101
#define WS_SCALE 102    // p2/denom
#define WS_DENOM 103
#define WS_CT    104    // 100
#define WS_ET    204    // 200 (16B aligned)
#define WS_H     404    // 50
#define WS_ADD   512    // 51257 raw scatter accumulator
#define WS_OUT   51776  // 51257 pre-logsoftmax vocab
#define WS_MS    103040 // NBLK5R*2 (m,s) pairs (1602 floats)
#define WS_PT    104960 // 101*2048 block partials [col][blk]

__device__ __forceinline__ float sigm(float x) { return 1.f / (1.f + expf(-x)); }

// ---------------- K1: LSTM step + q + p1/p2 ; zero add_buf ----------------
__global__ void k1_lstm(const float* __restrict__ y, const float* __restrict__ h0,
                        const float* __restrict__ c0,
                        const float* __restrict__ W_ih, const float* __restrict__ W_hh,
                        const float* __restrict__ b_ih, const float* __restrict__ b_hh,
                        const float* __restrict__ w_h_W, const float* __restrict__ w_h_b,
                        const float* __restrict__ l3_W, const float* __restrict__ l3_b,
                        const float* __restrict__ l4_W, const float* __restrict__ l4_b,
                        float* __restrict__ ws, float* __restrict__ out) {
    int t = threadIdx.x;
    if (blockIdx.x != 0) {
        float* add = ws + WS_ADD;
        for (int i = (blockIdx.x - 1) * 256 + t; i < NOUT; i += 63 * 256) add[i] = 0.f;
        return;
    }
    __shared__ float s_y[HS], s_h[HID], s_c[HID], s_g[4 * HID], s_hn[HID];
    if (t < HS) s_y[t] = y[t];
    if (t < HID) { s_h[t] = h0[t]; s_c[t] = c0[t]; }
    __syncthreads();
    if (t < 4 * HID) {
        float acc = b_ih[t] + b_hh[t];
        const float* wi = W_ih + t * HS;
        for (int k = 0; k < HS; ++k) acc += wi[k] * s_y[k];
        const float* wh = W_hh + t * HID;
        for (int k = 0; k < HID; ++k) acc += wh[k] * s_h[k];
        s_g[t] = acc;
    }
    __syncthreads();
    if (t < HID) {
        float ig = sigm(s_g[t]);
        float fg = sigm(s_g[HID + t]);
        float gg = tanhf(s_g[2 * HID + t]);
        float og = sigm(s_g[3 * HID + t]);
        float cn = fg * s_c[t] + ig * gg;
        float hn = og * tanhf(cn);
        s_hn[t] = hn;
        ws[WS_H + t] = hn;
        out[NOUT + t] = hn;          // h_new output
        out[NOUT + HID + t] = cn;    // c_new output
    }
    __syncthreads();
    if (t < FEAT) {
        float acc = w_h_b[t];
        const float* w = w_h_W + t * HID;
        for (int k = 0; k < HID; ++k) acc += w[k] * s_hn[k];
        ws[WS_Q + t] = acc;
    }
    if (t == 200) {
        float acc = l3_b[0];
        for (int k = 0; k < HID; ++k) acc += l3_W[k] * s_hn[k];
        ws[WS_P1] = sigm(acc);
    }
    if (t == 201) {
        float acc = l4_b[0];
        for (int k = 0; k < HID; ++k) acc += l4_W[k] * s_hn[k];
        ws[WS_P2] = sigm(acc);
    }
}

// ------- K23: half-wave-per-row pass over H. Lane l32 owns cols
// {l32, +32, +64, +96}; lanes 0-31 = row A, 32-63 = row B. 5-level butterfly
// per pair, 4 pairs (8 rows) per iteration. Wave-wide scatter at end.
// NOTE: 8 rows/iter scalar-col ownership is the proven sweet spot.
//  - 12 rows/iter: spills (R17, WRITE 20->53 MB)
//  - float4-cols + guarded prefetch: spills (R19, WRITE 20->53 MB) — hipcc
//    puts runtime-guarded conditional register arrays in scratch.
__global__ void __launch_bounds__(256, 8)
k23_fused(const float* __restrict__ H, const int* __restrict__ cont,
          float* __restrict__ ws, float* __restrict__ pt) {
    __shared__ float s_ct[4][FEAT];
    __shared__ float s_d[4];
    int t = threadIdx.x;
    int w = t >> 6, lane = t & 63;
    int l32 = lane & 31, half = lane >> 5;
    long wid = (long)blockIdx.x * 4 + w;
    long r0 = (wid * L) / NW23;
    long r1 = ((wid + 1) * L) / NW23;

    float q[4];
    q[0] = ws[WS_Q + l32];
    q[1] = ws[WS_Q + l32 + 32];
    q[2] = ws[WS_Q + l32 + 64];
    q[3] = (l32 < 4) ? ws[WS_Q + l32 + 96] : 0.f;

    float cacc[4] = {0.f, 0.f, 0.f, 0.f};
    float dacc = 0.f, my_e = 0.f;

    for (long r = r0; r < r1; r += 8) {
        float hh[4][4], pd[4];
#pragma unroll
        for (int p = 0; p < 4; ++p) {
            long row = r + 2 * p + half;
            if (row < r1) {
                const float* P = H + row * FEAT;
                hh[p][0] = P[l32];
                hh[p][1] = P[l32 + 32];
                hh[p][2] = P[l32 + 64];
                hh[p][3] = (l32 < 4) ? P[l32 + 96] : 0.f;
            } else {
                hh[p][0] = hh[p][1] = hh[p][2] = hh[p][3] = 0.f;
            }
        }
#pragma unroll
        for (int p = 0; p < 4; ++p)
            pd[p] = hh[p][0] * q[0] + hh[p][1] * q[1] + hh[p][2] * q[2] + hh[p][3] * q[3];
#pragma unroll
        for (int o = 1; o < 32; o <<= 1) {
#pragma unroll
            for (int p = 0; p < 4; ++p) pd[p] += __shfl_xor(pd[p], o);
        }
#pragma unroll
        for (int p = 0; p < 4; ++p) {
            float e = expf(pd[p]);            // own-half row's e
            float eo = __shfl_xor(e, 32);     // other half's e
            float eA = half ? eo : e;
            float eB = half ? e : eo;
            long rA = r + 2 * p, rB = rA + 1;
            if (rA < r1) {
                dacc += eA;
                my_e = ((int)(rA - r0) == lane) ? eA : my_e;
            }
            if (rB < r1) {
                dacc += eB;
                my_e = ((int)(rB - r0) == lane) ? eB : my_e;
            }
            cacc[0] += e * hh[p][0];
            cacc[1] += e * hh[p][1];
            cacc[2] += e * hh[p][2];
            cacc[3] += e * hh[p][3];
        }
    }
    // combine halves (rows A and B share col ownership)
#pragma unroll
    for (int k = 0; k < 4; ++k) cacc[k] += __shfl_xor(cacc[k], 32);
    // ---- wave-wide scatter: one atomic instruction per wave ----
    int cnt = (int)(r1 - r0);                  // ~30-31 <= 64
    if (lane < cnt) {
        int c = cont[r0 + lane];               // coalesced
        atomicAdd(ws + WS_ADD + c, my_e);
    }
    // ---- block partials ----
    if (half == 0) {
        s_ct[w][l32] = cacc[0];
        s_ct[w][l32 + 32] = cacc[1];
        s_ct[w][l32 + 64] = cacc[2];
        if (l32 < 4) s_ct[w][96 + l32] = cacc[3];
    }
    if (lane == 0) s_d[w] = dacc;
    __syncthreads();
    if (t < FEAT)
        pt[(size_t)t * NBLK23 + blockIdx.x] =
            s_ct[0][t] + s_ct[1][t] + s_ct[2][t] + s_ct[3][t];
    if (t == FEAT)
        pt[(size_t)FEAT * NBLK23 + blockIdx.x] = s_d[0] + s_d[1] + s_d[2] + s_d[3];
}

// ------- K3r: per-column partial reduce (plain, no fences) ----------
__global__ void k3r_reduce(const float* __restrict__ pt, float* __restrict__ ws) {
    __shared__ float sw[4];
    int col = blockIdx.x;           // 0..100 (100 = denom)
    int t = threadIdx.x;
    const float* p = pt + (size_t)col * NBLK23;
    float s = 0.f;
#pragma unroll
    for (int k = 0; k < NBLK23 / 256; ++k) s += p[t + k * 256];
#pragma unroll
    for (int o = 1; o < 64; o <<= 1) s += __shfl_xor(s, o);
    if ((t & 63) == 0) sw[t >> 6] = s;
    __syncthreads();
    if (t == 0) {
        float tot = sw[0] + sw[1] + sw[2] + sw[3];
        if (col < FEAT) ws[WS_CT + col] = tot;
        else ws[WS_DENOM] = tot;
    }
}

// ------- K4: 1 block: temp = [h ; ct/denom], e_t = sigmoid(l1), scale -------
__global__ void k4_et(const float* __restrict__ l1_W, const float* __restrict__ l1_b,
                      float* __restrict__ ws) {
    __shared__ float s_t[152];
    int t = threadIdx.x;
    float denom = ws[WS_DENOM];
    if (t < HID) s_t[t] = ws[WS_H + t];
    if (t < FEAT) s_t[HID + t] = ws[WS_CT + t] / denom;
    if (t == 0) ws[WS_SCALE] = ws[WS_P2] / denom;
    __syncthreads();
    if (t < 200) {
        float acc = l1_b[t];
        const float* wv = l1_W + t * 150;
        for (int k = 0; k < 150; ++k) acc += wv[k] * s_t[k];
        ws[WS_ET + t] = sigm(acc);
    }
}

// ------- K5: 4-threads-per-row GEMV (64 rows/block), explicit load array for
// MLP; out[r] = p1*(l2_W[r].e_t+b) + scale*add[r]; per-block (m,s) plain-store.
// NO fences, NO atomics, NO last-block work. ---------------------------------
__global__ void __launch_bounds__(256)
k5_vocab(const float* __restrict__ l2_W, const float* __restrict__ l2_b,
         float* __restrict__ ws, float* __restrict__ outv) {
    __shared__ float4 s_e[50];
    __shared__ float s_ms[8];
    int t = threadIdx.x, w = t >> 6, lane = t & 63;
    if (t < 50) s_e[t] = ((const float4*)(ws + WS_ET))[t];
    __syncthreads();
    float p1 = ws[WS_P1], scale = ws[WS_SCALE];
    const float* add = ws + WS_ADD;
    int row = blockIdx.x * 64 + (t >> 2);
    int q = t & 3;
    float m = -1e30f, s = 0.f;
    float acc = 0.f;
    if (row < CQ) {
        const float4* wrow = (const float4*)l2_W + (size_t)row * 50;
        float4 a[13];
#pragma unroll
        for (int j = 0; j < 12; ++j) a[j] = wrow[q + 4 * j];          // 12 independent loads
        a[12] = (q < 2) ? wrow[48 + q] : make_float4(0.f, 0.f, 0.f, 0.f);
#pragma unroll
        for (int j = 0; j < 12; ++j) {
            float4 b = s_e[q + 4 * j];
            acc += a[j].x * b.x + a[j].y * b.y + a[j].z * b.z + a[j].w * b.w;
        }
        if (q < 2) {
            float4 b = s_e[48 + q];
            acc += a[12].x * b.x + a[12].y * b.y + a[12].z * b.z + a[12].w * b.w;
        }
    }
    acc += __shfl_xor(acc, 1);
    acc += __shfl_xor(acc, 2);
    if (q == 0 && row < NOUT) {
        float val = (row < CQ) ? p1 * (acc + l2_b[row]) + scale * add[row]
                               : scale * add[row];
        outv[row] = val;
        m = val; s = 1.f;
    }
    // wave (m,s) butterfly
#pragma unroll
    for (int o = 1; o < 64; o <<= 1) {
        float mb = __shfl_xor(m, o), sb = __shfl_xor(s, o);
        float mn = fmaxf(m, mb);
        s = s * expf(m - mn) + sb * expf(mb - mn);
        m = mn;
    }
    if (lane == 0) { s_ms[w * 2] = m; s_ms[w * 2 + 1] = s; }
    __syncthreads();
    if (t == 0) {
        float mg = s_ms[0], sg = s_ms[1];
        for (int k = 1; k < 4; ++k) {
            float mb = s_ms[2 * k], sb = s_ms[2 * k + 1];
            float mn = fmaxf(mg, mb);
            sg = sg * expf(mg - mn) + sb * expf(mb - mn);
            mg = mn;
        }
        ws[WS_MS + 2 * blockIdx.x] = mg;
        ws[WS_MS + 2 * blockIdx.x + 1] = sg;
    }
}

// ------- K7c: redundant per-block lse reduce (1.6 KB, L2-hit) + subtract -----
__global__ void __launch_bounds__(256)
k7c_final(const float* __restrict__ outv, const float* __restrict__ ws,
          float* __restrict__ dout) {
    __shared__ float s_ms[8];
    __shared__ float s_lse;
    int t = threadIdx.x, w = t >> 6, lane = t & 63;
    const float* msbuf = ws + WS_MS;
    float mg = -1e30f, sg = 0.f;
    for (int k = t; k < NBLK5R; k += 256) {
        float mb = msbuf[2 * k], sb = msbuf[2 * k + 1];
        float mn = fmaxf(mg, mb);
        sg = sg * expf(mg - mn) + sb * expf(mb - mn);
        mg = mn;
    }
#pragma unroll
    for (int o = 1; o < 64; o <<= 1) {
        float mb = __shfl_xor(mg, o), sb = __shfl_xor(sg, o);
        float mn = fmaxf(mg, mb);
        sg = sg * expf(mg - mn) + sb * expf(mb - mn);
        mg = mn;
    }
    if (lane == 0) { s_ms[w * 2] = mg; s_ms[w * 2 + 1] = sg; }
    __syncthreads();
    if (t == 0) {
        float M = s_ms[0], S = s_ms[1];
        for (int k = 1; k < 4; ++k) {
            float mb = s_ms[2 * k], sb = s_ms[2 * k + 1];
            float mn = fmaxf(M, mb);
            S = S * expf(M - mn) + sb * expf(mb - mn);
            M = mn;
        }
        s_lse = M + logf(S);
    }
    __syncthreads();
    int j = blockIdx.x * 256 + t;
    if (j < NOUT) dout[j] = outv[j] - s_lse;
}

extern "C" void kernel_launch(void* const* d_in, const int* in_sizes, int n_in,
                              void* d_out, int out_size, void* d_ws, size_t ws_size,
                              hipStream_t stream) {
    const float* H    = (const float*)d_in[0];
    const float* y    = (const float*)d_in[1];
    const float* h0   = (const float*)d_in[2];
    const float* c0   = (const float*)d_in[3];
    const int*   cont = (const int*)d_in[4];
    // d_in[5] = ext scalar (1000), hardcoded
    const float* W_ih = (const float*)d_in[6];
    const float* W_hh = (const float*)d_in[7];
    const float* b_ih = (const float*)d_in[8];
    const float* b_hh = (const float*)d_in[9];
    const float* w_h_W = (const float*)d_in[10];
    const float* w_h_b = (const float*)d_in[11];
    const float* l1_W = (const float*)d_in[12];
    const float* l1_b = (const float*)d_in[13];
    const float* l2_W = (const float*)d_in[14];
    const float* l2_b = (const float*)d_in[15];
    const float* l3_W = (const float*)d_in[16];
    const float* l3_b = (const float*)d_in[17];
    const float* l4_W = (const float*)d_in[18];
    const float* l4_b = (const float*)d_in[19];

    float* ws  = (float*)d_ws;
    float* out = (float*)d_out;

    k1_lstm<<<64, 256, 0, stream>>>(y, h0, c0, W_ih, W_hh, b_ih, b_hh,
                                    w_h_W, w_h_b, l3_W, l3_b, l4_W, l4_b, ws, out);

    k23_fused<<<NBLK23, 256, 0, stream>>>(H, cont, ws, ws + WS_PT);

    k3r_reduce<<<NCOL, 256, 0, stream>>>(ws + WS_PT, ws);

    k4_et<<<1, 256, 0, stream>>>(l1_W, l1_b, ws);

    k5_vocab<<<NBLK5R, 256, 0, stream>>>(l2_W, l2_b, ws, ws + WS_OUT);

    k7c_final<<<(NOUT + 255) / 256, 256, 0, stream>>>(ws + WS_OUT, ws, out);
}